// Round 5
// baseline (775.273 us; speedup 1.0000x reference)
//
#include <hip/hip_runtime.h>
#include <math.h>

#define D_MODEL 1024
#define N_TOK   8192
#define SEQ_L   1024
#define N_HEAD  16
#define HEAD_D  64
#define FF_DIM  4096

typedef __attribute__((ext_vector_type(8))) short bf16x8;   // 8 bf16 = 4 VGPRs
typedef __attribute__((ext_vector_type(4))) short short4v;
typedef __attribute__((ext_vector_type(2))) int  int2v;
typedef __attribute__((ext_vector_type(4))) float f32x4;

#define MFMA16(a, b, c) __builtin_amdgcn_mfma_f32_16x16x32_bf16((a), (b), (c), 0, 0, 0)

// async global->LDS, 16B per lane; LDS dest = wave-uniform base + lane*16
#define GLD16(gp, lp) __builtin_amdgcn_global_load_lds(                      \
    (const __attribute__((address_space(1))) void*)(gp),                     \
    (__attribute__((address_space(3))) void*)(lp), 16, 0, 0)

#if defined(__has_builtin)
#if __has_builtin(__builtin_amdgcn_exp2f)
#define EXP2F(x) __builtin_amdgcn_exp2f(x)
#else
#define EXP2F(x) exp2f(x)
#endif
#else
#define EXP2F(x) exp2f(x)
#endif

__device__ __forceinline__ short f2bf(float f) {   // fp32 -> bf16 (RNE)
    unsigned u = __float_as_uint(f);
    u += 0x7fffu + ((u >> 16) & 1u);
    return (short)(u >> 16);
}

// pack two fp32 -> two bf16 (round-nearest-up) in one v_perm
__device__ __forceinline__ int pack2bf(float a, float b) {
    unsigned ua = __float_as_uint(a) + 0x8000u;
    unsigned ub = __float_as_uint(b) + 0x8000u;
    return __builtin_amdgcn_perm(ub, ua, 0x07060302u);
}

// ---------------------------------------------------------------------------
// LayerNorm fp32 -> bf16. One block (256 thr) per token.
// ---------------------------------------------------------------------------
__global__ __launch_bounds__(256) void ln_kernel(const float* __restrict__ x,
                                                 const float* __restrict__ g,
                                                 const float* __restrict__ b,
                                                 short* __restrict__ o)
{
    int t = blockIdx.x;
    const float* xr = x + (size_t)t * D_MODEL;
    short* orow = o + (size_t)t * D_MODEL;
    float vals[4];
    float lsum = 0.f, lsq = 0.f;
#pragma unroll
    for (int i = 0; i < 4; i++) {
        float v = xr[threadIdx.x + i * 256];
        vals[i] = v; lsum += v; lsq += v * v;
    }
#pragma unroll
    for (int off = 32; off > 0; off >>= 1) {
        lsum += __shfl_down(lsum, off);
        lsq  += __shfl_down(lsq,  off);
    }
    __shared__ float red[8];
    int wid = threadIdx.x >> 6, lane = threadIdx.x & 63;
    if (lane == 0) { red[wid] = lsum; red[4 + wid] = lsq; }
    __syncthreads();
    if (threadIdx.x == 0) {
        red[0] = red[0] + red[1] + red[2] + red[3];
        red[4] = red[4] + red[5] + red[6] + red[7];
    }
    __syncthreads();
    float mean = red[0] * (1.f / D_MODEL);
    float var  = red[4] * (1.f / D_MODEL) - mean * mean;
    float inv  = rsqrtf(var + 1e-5f);
#pragma unroll
    for (int i = 0; i < 4; i++) {
        int c = threadIdx.x + i * 256;
        orow[c] = f2bf((vals[i] - mean) * inv * g[c] + b[c]);
    }
}

// ---------------------------------------------------------------------------
// Transpose + cast: src fp32 [R,C] -> dst bf16 [C,R]. 32x32 tiles.
// ---------------------------------------------------------------------------
__global__ __launch_bounds__(256) void transpose_cast(const float* __restrict__ src,
                                                      short* __restrict__ dst,
                                                      int R, int C)
{
    __shared__ float t[32][33];
    int r0 = blockIdx.y * 32, c0 = blockIdx.x * 32;
    int tid = threadIdx.x;
#pragma unroll
    for (int i = 0; i < 4; i++) {
        int idx = i * 256 + tid;
        int r = idx >> 5, c = idx & 31;
        t[r][c] = src[(size_t)(r0 + r) * C + c0 + c];
    }
    __syncthreads();
#pragma unroll
    for (int i = 0; i < 4; i++) {
        int idx = i * 256 + tid;
        int rr = idx >> 5, cc = idx & 31;
        dst[(size_t)(c0 + rr) * R + r0 + cc] = f2bf(t[cc][rr]);
    }
}

// ---------------------------------------------------------------------------
// bf16 MFMA GEMM (m97 structure): C[M,N] = epilogue(A[M,K] @ Bt[N,K]^T)
// 128x128 tile, BK=32, 256 thr = 4 waves, each wave 64x64 via 4x4 16x16 frags.
// C/D layout: col=lane&15, row=quad*4+reg.
// Modes:
//   qkv=1: N=3072 fused QKV. col>>10 selects segment: 0/1 -> bf16 store to
//          Cb + seg*8M (qb,kbf contiguous at 16MB stride), 2 -> transposed
//          V store to Cvt ([(b*H+h)*64+d][SEQ_L]); bias from bias/bias2/bias3.
//   else:  +bias, optional quick_gelu, optional fp32 resid, store Cf or Cb.
// ---------------------------------------------------------------------------
__global__ __launch_bounds__(256) void gemm_bf16(
    const short* __restrict__ A, int lda,
    const short* __restrict__ Bt, int ldb,
    const float* __restrict__ bias,
    const float* __restrict__ bias2,
    const float* __restrict__ bias3,
    const float* __restrict__ resid,
    float* __restrict__ Cf, short* __restrict__ Cb, short* __restrict__ Cvt,
    int ldc, int K, int act, int qkv)
{
    __shared__ __align__(16) short sA[128 * 32];
    __shared__ __align__(16) short sB[128 * 32];
    const int tid = threadIdx.x;
    const int lane = tid & 63, wave = tid >> 6;
    const int quad = lane >> 4, l15 = lane & 15;
    const int bm = blockIdx.y * 128, bn = blockIdx.x * 128;
    const int wm = (wave >> 1) * 64, wn = (wave & 1) * 64;

    const int ca = tid, cb = tid + 256;
    const int ra = ca >> 2, ka = (ca & 3) << 3;
    const int rb = cb >> 2, kb = (cb & 3) << 3;

    f32x4 acc[4][4];
#pragma unroll
    for (int i = 0; i < 4; i++)
#pragma unroll
        for (int j = 0; j < 4; j++) acc[i][j] = (f32x4){0.f, 0.f, 0.f, 0.f};

    for (int k0 = 0; k0 < K; k0 += 32) {
        __syncthreads();
        GLD16(A  + (size_t)(bm + ra) * lda + k0 + ka, &sA[ca * 8]);
        GLD16(A  + (size_t)(bm + rb) * lda + k0 + kb, &sA[cb * 8]);
        GLD16(Bt + (size_t)(bn + ra) * ldb + k0 + ka, &sB[ca * 8]);
        GLD16(Bt + (size_t)(bn + rb) * ldb + k0 + kb, &sB[cb * 8]);
        __syncthreads();
        bf16x8 af[4], bfr[4];
#pragma unroll
        for (int mt = 0; mt < 4; mt++)
            af[mt] = *(const bf16x8*)&sA[(wm + mt * 16 + l15) * 32 + quad * 8];
#pragma unroll
        for (int nt = 0; nt < 4; nt++)
            bfr[nt] = *(const bf16x8*)&sB[(wn + nt * 16 + l15) * 32 + quad * 8];
#pragma unroll
        for (int mt = 0; mt < 4; mt++)
#pragma unroll
            for (int nt = 0; nt < 4; nt++)
                acc[mt][nt] = MFMA16(af[mt], bfr[nt], acc[mt][nt]);
    }

#pragma unroll
    for (int mt = 0; mt < 4; mt++)
#pragma unroll
        for (int nt = 0; nt < 4; nt++) {
            int row0 = bm + wm + mt * 16 + quad * 4;
            int col  = bn + wn + nt * 16 + l15;
            if (qkv) {
                int seg = col >> 10, cloc = col & 1023;
                const float* bp = (seg == 0) ? bias : (seg == 1) ? bias2 : bias3;
                float bval = bp[cloc];
                if (seg == 2) {
                    // V transposed store: page=(b*H+h)*64+d, index = seq pos
                    int bb = row0 >> 10, l0 = row0 & 1023;
                    size_t page = (size_t)(bb * N_HEAD + (cloc >> 6)) * HEAD_D + (cloc & 63);
                    short4v pk = { f2bf(acc[mt][nt][0] + bval), f2bf(acc[mt][nt][1] + bval),
                                   f2bf(acc[mt][nt][2] + bval), f2bf(acc[mt][nt][3] + bval) };
                    *(short4v*)&Cvt[page * SEQ_L + l0] = pk;
                } else {
                    short* dst = Cb + (size_t)seg * ((size_t)N_TOK * D_MODEL);
#pragma unroll
                    for (int r = 0; r < 4; r++)
                        dst[(size_t)(row0 + r) * D_MODEL + cloc] = f2bf(acc[mt][nt][r] + bval);
                }
            } else {
#pragma unroll
                for (int r = 0; r < 4; r++) {
                    int row = row0 + r;
                    float v = acc[mt][nt][r] + bias[col];
                    if (act) v = v / (1.f + __expf(-1.702f * v));   // quick_gelu
                    if (resid) v += resid[(size_t)row * ldc + col];
                    if (Cb) Cb[(size_t)row * ldc + col] = f2bf(v);
                    else    Cf[(size_t)row * ldc + col] = v;
                }
            }
        }
}

// ---------------------------------------------------------------------------
// Flash attention, bf16 MFMA, S^T form, K-step=128 (8 sub-tiles of 16 keys).
// __launch_bounds__(256,2): ~256 VGPR budget so all K(16)+V(16) dwordx4
// loads stay in flight. Softmax in log2 domain (exp2, scale folded into the
// mask FMA). P packed pairwise via v_perm -> ds_write_b64 into a per-wave
// slab (rows 272 B: 2-way bank alias only). No block barriers in K-loop.
// ---------------------------------------------------------------------------
__global__ __launch_bounds__(256, 2) void attn_kernel(
    const short* __restrict__ Q, const short* __restrict__ Kb,
    const short* __restrict__ Vt, const int* __restrict__ mask,
    short* __restrict__ O)
{
    __shared__ __align__(16) float sMB[SEQ_L];
    __shared__ __align__(16) short sP[4][16 * 136];   // per-wave [16 q][136]
    __shared__ __align__(16) float sAl[4][20];

    const int g = blockIdx.x;
    const int xcd = g & 7, slot = g >> 3;
    const int qt = slot & 15, bhl = slot >> 4;
    const int bh = xcd * 16 + bhl;
    const int b = bh >> 4, h = bh & 15;

    const int tid = threadIdx.x;
    const int wave = tid >> 6, lane = tid & 63;
    const int quad = lane >> 4, l15 = lane & 15;

    for (int i = tid; i < SEQ_L; i += 256)
        sMB[i] = (mask[b * SEQ_L + i] > 0) ? 0.f : -1e30f;   // log2-domain mask
    __syncthreads();

    const int qbase = b * SEQ_L + qt * 64;
    const short* qp = Q + (size_t)(qbase + wave * 16 + l15) * D_MODEL + h * HEAD_D + quad * 8;
    bf16x8 qf0 = *(const bf16x8*)qp;
    bf16x8 qf1 = *(const bf16x8*)(qp + 32);

    // wave-uniform bases + per-lane invariant offsets
    const short* Kbh = Kb + (size_t)b * SEQ_L * D_MODEL + h * HEAD_D;
    const short* Vbh = Vt + (size_t)(b * N_HEAD + h) * HEAD_D * SEQ_L;
    const int klane = (l15 << 10) + (quad << 3);          // l15*D + quad*8
    const int vlane = (l15 << 10) + (quad << 3);          // l15*SEQ_L + quad*8

    f32x4 o4[4];
#pragma unroll
    for (int nt = 0; nt < 4; nt++) o4[nt] = (f32x4){0.f, 0.f, 0.f, 0.f};
    float mrow = -1e30f, lrow = 0.f;     // per-lane: q = l15 of this wave
    short* pslab = &sP[wave][0];         // per-wave private [16 q][136]
    const float CSC = 0.125f * 1.4426950408889634f;   // scale * log2(e)

    for (int kt = 0; kt < SEQ_L / 128; kt++) {
        const short* Kt = Kbh + (size_t)kt * 128 * D_MODEL;
        const short* Vk = Vbh + kt * 128;
        // ---- issue all 16 K loads ----
        bf16x8 kf[8][2];
#pragma unroll
        for (int sub = 0; sub < 8; sub++) {
            const short* kp = Kt + sub * 16 * D_MODEL + klane;
            kf[sub][0] = *(const bf16x8*)kp;
            kf[sub][1] = *(const bf16x8*)(kp + 32);
        }
        // ---- S^T = K·Q^T : D[m=key][n=q] ----
        f32x4 s[8];
#pragma unroll
        for (int sub = 0; sub < 8; sub++) {
            s[sub] = (f32x4){0.f, 0.f, 0.f, 0.f};
            s[sub] = MFMA16(kf[sub][0], qf0, s[sub]);
            s[sub] = MFMA16(kf[sub][1], qf1, s[sub]);
        }
        // ---- issue all 16 V loads (latency hides under softmax) ----
        bf16x8 vf[4][4];
#pragma unroll
        for (int nt = 0; nt < 4; nt++)
#pragma unroll
            for (int c = 0; c < 4; c++)
                vf[nt][c] = *(const bf16x8*)(Vk + (size_t)nt * 16 * SEQ_L + vlane + c * 32);
        // ---- scale+mask in one FMA (log2 domain) ----
#pragma unroll
        for (int sub = 0; sub < 8; sub++) {
            f32x4 mb = *(const f32x4*)&sMB[kt * 128 + sub * 16 + quad * 4];
#pragma unroll
            for (int r = 0; r < 4; r++) s[sub][r] = s[sub][r] * CSC + mb[r];
        }
        // ---- per-lane max over 32 scores + 2 shuffles ----
        f32x4 mx4 = s[0];
#pragma unroll
        for (int sub = 1; sub < 8; sub++)
#pragma unroll
            for (int r = 0; r < 4; r++) mx4[r] = fmaxf(mx4[r], s[sub][r]);
        float pmax = fmaxf(fmaxf(mx4[0], mx4[1]), fmaxf(mx4[2], mx4[3]));
        pmax = fmaxf(pmax, __shfl_xor(pmax, 16));
        pmax = fmaxf(pmax, __shfl_xor(pmax, 32));
        float mnew = fmaxf(mrow, pmax);
        float alpha = EXP2F(mrow - mnew);
        mrow = mnew;
        if (quad == 0) sAl[wave][l15] = alpha;   // broadcast to O rows

        // ---- exp2 + pairwise pack + P writes ----
        float ls = 0.f;
#pragma unroll
        for (int sub = 0; sub < 8; sub++) {
            float p0 = EXP2F(s[sub][0] - mnew);
            float p1 = EXP2F(s[sub][1] - mnew);
            float p2 = EXP2F(s[sub][2] - mnew);
            float p3 = EXP2F(s[sub][3] - mnew);
            ls += (p0 + p1) + (p2 + p3);
            int2v pk = { pack2bf(p0, p1), pack2bf(p2, p3) };
            *(int2v*)&pslab[l15 * 136 + sub * 16 + quad * 4] = pk;
        }
        ls += __shfl_xor(ls, 16);
        ls += __shfl_xor(ls, 32);
        lrow = lrow * alpha + ls;

        // ---- rescale O by alpha (read per-row broadcast) ----
        f32x4 av = *(const f32x4*)&sAl[wave][quad * 4];
#pragma unroll
        for (int nt = 0; nt < 4; nt++)
#pragma unroll
            for (int r = 0; r < 4; r++) o4[nt][r] *= av[r];

        // ---- PV: P A-frags from slab (4 chunks of 32 keys) ----
        bf16x8 pf[4];
#pragma unroll
        for (int c = 0; c < 4; c++)
            pf[c] = *(const bf16x8*)&pslab[l15 * 136 + c * 32 + quad * 8];
#pragma unroll
        for (int nt = 0; nt < 4; nt++)
#pragma unroll
            for (int c = 0; c < 4; c++)
                o4[nt] = MFMA16(pf[c], vf[nt][c], o4[nt]);
    }
    // final 1/l broadcast to O rows
    if (quad == 0) sAl[wave][l15] = 1.f / lrow;
    f32x4 iv = *(const f32x4*)&sAl[wave][quad * 4];
#pragma unroll
    for (int nt = 0; nt < 4; nt++)
#pragma unroll
        for (int r = 0; r < 4; r++)
            O[(size_t)(qbase + wave * 16 + quad * 4 + r) * D_MODEL
              + h * HEAD_D + nt * 16 + l15] = f2bf(o4[nt][r] * iv[r]);
}

// ---------------------------------------------------------------------------
// Launch
// ---------------------------------------------------------------------------
extern "C" void kernel_launch(void* const* d_in, const int* in_sizes, int n_in,
                              void* d_out, int out_size, void* d_ws, size_t ws_size,
                              hipStream_t stream)
{
    const float* x     = (const float*)d_in[0];
    const int*   amask = (const int*)  d_in[1];
    const float* wq    = (const float*)d_in[2];
    const float* bq    = (const float*)d_in[3];
    const float* wk    = (const float*)d_in[4];
    const float* bk    = (const float*)d_in[5];
    const float* wv    = (const float*)d_in[6];
    const float* bv    = (const float*)d_in[7];
    const float* wo    = (const float*)d_in[8];
    const float* bo    = (const float*)d_in[9];
    const float* ln1s  = (const float*)d_in[10];
    const float* ln1b  = (const float*)d_in[11];
    const float* ln2s  = (const float*)d_in[12];
    const float* ln2b  = (const float*)d_in[13];
    const float* w1    = (const float*)d_in[14];
    const float* b1    = (const float*)d_in[15];
    const float* w2    = (const float*)d_in[16];
    const float* b2    = (const float*)d_in[17];
    float* out = (float*)d_out;

    // workspace layout (bytes; peak 104 MB, proven available)
    char* w = (char*)d_ws;
    short* wqkvt = (short*)(w + (size_t)0);          // [3072][1024] bf16, 6MB
    short* wot   = (short*)(w + ((size_t)6  << 20));
    short* w1t   = (short*)(w + ((size_t)8  << 20));
    short* w2t   = (short*)(w + ((size_t)16 << 20));
    short* hb    = (short*)(w + ((size_t)24 << 20)); // LN1 out, later LN2 out
    short* qb    = (short*)(w + ((size_t)40 << 20)); // qb,kbf contiguous:
    short* kbf   = (short*)(w + ((size_t)56 << 20)); //   16MB stride for qkv mode
    short* attnb = (short*)(w + ((size_t)72 << 20));
    short* vtb   = (short*)(w + ((size_t)88 << 20));
    short* ffb   = qb;   // q/k/vt dead by MLP1 (64 MB span 40..104)

    dim3 blk(256);

    // weight prep: W [K,N] fp32 -> W^T [N,K] bf16 (QKV stacked into one)
    transpose_cast<<<dim3(32, 32),  blk, 0, stream>>>(wq, wqkvt,              1024, 1024);
    transpose_cast<<<dim3(32, 32),  blk, 0, stream>>>(wk, wqkvt + 1024 * 1024, 1024, 1024);
    transpose_cast<<<dim3(32, 32),  blk, 0, stream>>>(wv, wqkvt + 2048 * 1024, 1024, 1024);
    transpose_cast<<<dim3(32, 32),  blk, 0, stream>>>(wo, wot, 1024, 1024);
    transpose_cast<<<dim3(128, 32), blk, 0, stream>>>(w1, w1t, 1024, 4096);
    transpose_cast<<<dim3(32, 128), blk, 0, stream>>>(w2, w2t, 4096, 1024);

    // 1) h = LN1(x) -> bf16
    ln_kernel<<<N_TOK, blk, 0, stream>>>(x, ln1s, ln1b, hb);

    // 2) fused QKV GEMM: writes qb, kbf, and V directly transposed (vtb)
    gemm_bf16<<<dim3(3 * D_MODEL / 128, N_TOK / 128), blk, 0, stream>>>(
        hb, 1024, wqkvt, 1024, bq, bk, bv, nullptr,
        nullptr, qb, vtb, 1024, 1024, 0, 1);

    // 3) flash attention -> attnb (bf16); 1-D grid, XCD swizzle inside
    attn_kernel<<<dim3(2048), blk, 0, stream>>>(qb, kbf, vtb, amask, attnb);

    // 4) out = x + attn @ wo + bo  (fp32 out)
    gemm_bf16<<<dim3(D_MODEL / 128, N_TOK / 128), blk, 0, stream>>>(
        attnb, 1024, wot, 1024, bo, nullptr, nullptr, x,
        out, nullptr, nullptr, 1024, 1024, 0, 0);

    // 5) h = LN2(out) -> bf16
    ln_kernel<<<N_TOK, blk, 0, stream>>>(out, ln2s, ln2b, hb);

    // 6) MLP
    gemm_bf16<<<dim3(FF_DIM / 128, N_TOK / 128), blk, 0, stream>>>(
        hb, 1024, w1t, 1024, b1, nullptr, nullptr, nullptr,
        nullptr, ffb, nullptr, 4096, 1024, 1, 0);
    gemm_bf16<<<dim3(D_MODEL / 128, N_TOK / 128), blk, 0, stream>>>(
        ffb, 4096, w2t, 4096, b2, nullptr, nullptr, out,
        out, nullptr, nullptr, 1024, 4096, 0, 0);
}

// Round 6
// 652.621 us; speedup vs baseline: 1.1879x; 1.1879x over previous
//
#include <hip/hip_runtime.h>
#include <math.h>

#define D_MODEL 1024
#define N_TOK   8192
#define SEQ_L   1024
#define N_HEAD  16
#define HEAD_D  64
#define FF_DIM  4096

typedef __attribute__((ext_vector_type(8))) short bf16x8;   // 8 bf16 = 4 VGPRs
typedef __attribute__((ext_vector_type(4))) short short4v;
typedef __attribute__((ext_vector_type(2))) int  int2v;
typedef __attribute__((ext_vector_type(4))) float f32x4;

#define MFMA16(a, b, c) __builtin_amdgcn_mfma_f32_16x16x32_bf16((a), (b), (c), 0, 0, 0)

// async global->LDS, 16B per lane; LDS dest = wave-uniform base + lane*16
#define GLD16(gp, lp) __builtin_amdgcn_global_load_lds(                      \
    (const __attribute__((address_space(1))) void*)(gp),                     \
    (__attribute__((address_space(3))) void*)(lp), 16, 0, 0)

#if defined(__has_builtin)
#if __has_builtin(__builtin_amdgcn_exp2f)
#define EXP2F(x) __builtin_amdgcn_exp2f(x)
#else
#define EXP2F(x) exp2f(x)
#endif
#else
#define EXP2F(x) exp2f(x)
#endif

__device__ __forceinline__ short f2bf(float f) {   // fp32 -> bf16 (RNE)
    unsigned u = __float_as_uint(f);
    u += 0x7fffu + ((u >> 16) & 1u);
    return (short)(u >> 16);
}

// pack two fp32 -> two bf16 (round-nearest-up) in one v_perm
__device__ __forceinline__ int pack2bf(float a, float b) {
    unsigned ua = __float_as_uint(a) + 0x8000u;
    unsigned ub = __float_as_uint(b) + 0x8000u;
    return __builtin_amdgcn_perm(ub, ua, 0x07060302u);
}

// ---------------------------------------------------------------------------
// LayerNorm fp32 -> bf16. One block (256 thr) per token.
// ---------------------------------------------------------------------------
__global__ __launch_bounds__(256) void ln_kernel(const float* __restrict__ x,
                                                 const float* __restrict__ g,
                                                 const float* __restrict__ b,
                                                 short* __restrict__ o)
{
    int t = blockIdx.x;
    const float* xr = x + (size_t)t * D_MODEL;
    short* orow = o + (size_t)t * D_MODEL;
    float vals[4];
    float lsum = 0.f, lsq = 0.f;
#pragma unroll
    for (int i = 0; i < 4; i++) {
        float v = xr[threadIdx.x + i * 256];
        vals[i] = v; lsum += v; lsq += v * v;
    }
#pragma unroll
    for (int off = 32; off > 0; off >>= 1) {
        lsum += __shfl_down(lsum, off);
        lsq  += __shfl_down(lsq,  off);
    }
    __shared__ float red[8];
    int wid = threadIdx.x >> 6, lane = threadIdx.x & 63;
    if (lane == 0) { red[wid] = lsum; red[4 + wid] = lsq; }
    __syncthreads();
    if (threadIdx.x == 0) {
        red[0] = red[0] + red[1] + red[2] + red[3];
        red[4] = red[4] + red[5] + red[6] + red[7];
    }
    __syncthreads();
    float mean = red[0] * (1.f / D_MODEL);
    float var  = red[4] * (1.f / D_MODEL) - mean * mean;
    float inv  = rsqrtf(var + 1e-5f);
#pragma unroll
    for (int i = 0; i < 4; i++) {
        int c = threadIdx.x + i * 256;
        orow[c] = f2bf((vals[i] - mean) * inv * g[c] + b[c]);
    }
}

// ---------------------------------------------------------------------------
// mask int -> fp32 additive (log2-domain): 0 or -1e30
// ---------------------------------------------------------------------------
__global__ __launch_bounds__(256) void mask_kernel(const int* __restrict__ m,
                                                   float* __restrict__ fm)
{
    int i = blockIdx.x * 256 + threadIdx.x;
    fm[i] = (m[i] > 0) ? 0.f : -1e30f;
}

// ---------------------------------------------------------------------------
// Transpose + cast: src fp32 [R,C] -> dst bf16 [C,R]. 32x32 tiles.
// ---------------------------------------------------------------------------
__global__ __launch_bounds__(256) void transpose_cast(const float* __restrict__ src,
                                                      short* __restrict__ dst,
                                                      int R, int C)
{
    __shared__ float t[32][33];
    int r0 = blockIdx.y * 32, c0 = blockIdx.x * 32;
    int tid = threadIdx.x;
#pragma unroll
    for (int i = 0; i < 4; i++) {
        int idx = i * 256 + tid;
        int r = idx >> 5, c = idx & 31;
        t[r][c] = src[(size_t)(r0 + r) * C + c0 + c];
    }
    __syncthreads();
#pragma unroll
    for (int i = 0; i < 4; i++) {
        int idx = i * 256 + tid;
        int rr = idx >> 5, cc = idx & 31;
        dst[(size_t)(c0 + rr) * R + r0 + cc] = f2bf(t[cc][rr]);
    }
}

// ---------------------------------------------------------------------------
// bf16 MFMA GEMM (m97 structure): C[M,N] = epilogue(A[M,K] @ Bt[N,K]^T)
// 128x128 tile, BK=32, 256 thr = 4 waves, each wave 64x64 via 4x4 16x16 frags.
// C/D layout: col=lane&15, row=quad*4+reg.
// Modes:
//   qkv=1: N=3072 fused QKV. col>>10 selects segment: 0/1 -> bf16 store to
//          Cb + seg*8M (qb,kbf contiguous at 16MB stride), 2 -> transposed
//          V store to Cvt ([(b*H+h)*64+d][SEQ_L]); bias from bias/bias2/bias3.
//   else:  +bias, optional quick_gelu, optional fp32 resid, store Cf or Cb.
// ---------------------------------------------------------------------------
__global__ __launch_bounds__(256) void gemm_bf16(
    const short* __restrict__ A, int lda,
    const short* __restrict__ Bt, int ldb,
    const float* __restrict__ bias,
    const float* __restrict__ bias2,
    const float* __restrict__ bias3,
    const float* __restrict__ resid,
    float* __restrict__ Cf, short* __restrict__ Cb, short* __restrict__ Cvt,
    int ldc, int K, int act, int qkv)
{
    __shared__ __align__(16) short sA[128 * 32];
    __shared__ __align__(16) short sB[128 * 32];
    const int tid = threadIdx.x;
    const int lane = tid & 63, wave = tid >> 6;
    const int quad = lane >> 4, l15 = lane & 15;
    const int bm = blockIdx.y * 128, bn = blockIdx.x * 128;
    const int wm = (wave >> 1) * 64, wn = (wave & 1) * 64;

    const int ca = tid, cb = tid + 256;
    const int ra = ca >> 2, ka = (ca & 3) << 3;
    const int rb = cb >> 2, kb = (cb & 3) << 3;

    f32x4 acc[4][4];
#pragma unroll
    for (int i = 0; i < 4; i++)
#pragma unroll
        for (int j = 0; j < 4; j++) acc[i][j] = (f32x4){0.f, 0.f, 0.f, 0.f};

    for (int k0 = 0; k0 < K; k0 += 32) {
        __syncthreads();
        GLD16(A  + (size_t)(bm + ra) * lda + k0 + ka, &sA[ca * 8]);
        GLD16(A  + (size_t)(bm + rb) * lda + k0 + kb, &sA[cb * 8]);
        GLD16(Bt + (size_t)(bn + ra) * ldb + k0 + ka, &sB[ca * 8]);
        GLD16(Bt + (size_t)(bn + rb) * ldb + k0 + kb, &sB[cb * 8]);
        __syncthreads();
        bf16x8 af[4], bfr[4];
#pragma unroll
        for (int mt = 0; mt < 4; mt++)
            af[mt] = *(const bf16x8*)&sA[(wm + mt * 16 + l15) * 32 + quad * 8];
#pragma unroll
        for (int nt = 0; nt < 4; nt++)
            bfr[nt] = *(const bf16x8*)&sB[(wn + nt * 16 + l15) * 32 + quad * 8];
#pragma unroll
        for (int mt = 0; mt < 4; mt++)
#pragma unroll
            for (int nt = 0; nt < 4; nt++)
                acc[mt][nt] = MFMA16(af[mt], bfr[nt], acc[mt][nt]);
    }

#pragma unroll
    for (int mt = 0; mt < 4; mt++)
#pragma unroll
        for (int nt = 0; nt < 4; nt++) {
            int row0 = bm + wm + mt * 16 + quad * 4;
            int col  = bn + wn + nt * 16 + l15;
            if (qkv) {
                int seg = col >> 10, cloc = col & 1023;
                const float* bp = (seg == 0) ? bias : (seg == 1) ? bias2 : bias3;
                float bval = bp[cloc];
                if (seg == 2) {
                    // V transposed store: page=(b*H+h)*64+d, index = seq pos
                    int bb = row0 >> 10, l0 = row0 & 1023;
                    size_t page = (size_t)(bb * N_HEAD + (cloc >> 6)) * HEAD_D + (cloc & 63);
                    short4v pk = { f2bf(acc[mt][nt][0] + bval), f2bf(acc[mt][nt][1] + bval),
                                   f2bf(acc[mt][nt][2] + bval), f2bf(acc[mt][nt][3] + bval) };
                    *(short4v*)&Cvt[page * SEQ_L + l0] = pk;
                } else {
                    short* dst = Cb + (size_t)seg * ((size_t)N_TOK * D_MODEL);
#pragma unroll
                    for (int r = 0; r < 4; r++)
                        dst[(size_t)(row0 + r) * D_MODEL + cloc] = f2bf(acc[mt][nt][r] + bval);
                }
            } else {
#pragma unroll
                for (int r = 0; r < 4; r++) {
                    int row = row0 + r;
                    float v = acc[mt][nt][r] + bias[col];
                    if (act) v = v / (1.f + __expf(-1.702f * v));   // quick_gelu
                    if (resid) v += resid[(size_t)row * ldc + col];
                    if (Cb) Cb[(size_t)row * ldc + col] = f2bf(v);
                    else    Cf[(size_t)row * ldc + col] = v;
                }
            }
        }
}

// ---------------------------------------------------------------------------
// Flash attention, bf16 MFMA, S^T form, K-step=128, m97-style LDS staging.
// K-tile (128x64) and V^T-tile (64x128) staged via global_load_lds into
// chunk-major LDS layouts (slot = kchunk*rows + row, 16B slots) so frag
// ds_read_b128 sweeps all 32 banks per 8-lane group (conflict-free) and
// data loads consume NO VGPRs (fixes the R3-R5 serialized-load chain).
// Softmax: log2 domain, per-lane m/l (S^T: lane&15 = q). Mask precomputed
// as fp32 in global. P transposed via per-wave LDS slab.
// ---------------------------------------------------------------------------
__global__ __launch_bounds__(256) void attn_kernel(
    const short* __restrict__ Q, const short* __restrict__ Kb,
    const short* __restrict__ Vt, const float* __restrict__ fmask,
    short* __restrict__ O)
{
    __shared__ __align__(16) short sK[8192];        // 16KB: slot=kc*128+key
    __shared__ __align__(16) short sV[8192];        // 16KB: slot=kc2*64+d
    __shared__ __align__(16) short sP[4][16 * 136]; // per-wave [16 q][136]
    __shared__ __align__(16) float sAl[4][20];

    const int g = blockIdx.x;
    const int xcd = g & 7, slot = g >> 3;
    const int qt = slot & 15, bhl = slot >> 4;
    const int bh = xcd * 16 + bhl;
    const int b = bh >> 4, h = bh & 15;

    const int tid = threadIdx.x;
    const int wave = tid >> 6, lane = tid & 63;
    const int quad = lane >> 4, l15 = lane & 15;

    const int qbase = b * SEQ_L + qt * 64;
    const short* qp = Q + (size_t)(qbase + wave * 16 + l15) * D_MODEL + h * HEAD_D + quad * 8;
    bf16x8 qf0 = *(const bf16x8*)qp;
    bf16x8 qf1 = *(const bf16x8*)(qp + 32);

    const short* Kbh = Kb + (size_t)b * SEQ_L * D_MODEL + h * HEAD_D;
    const short* Vbh = Vt + (size_t)(b * N_HEAD + h) * HEAD_D * SEQ_L;
    const float* mk  = fmask + b * SEQ_L;

    f32x4 o4[4];
#pragma unroll
    for (int nt = 0; nt < 4; nt++) o4[nt] = (f32x4){0.f, 0.f, 0.f, 0.f};
    float mrow = -1e30f, lrow = 0.f;     // per-lane: q = l15 of this wave
    short* pslab = &sP[wave][0];         // per-wave private [16 q][136]
    const float CSC = 0.125f * 1.4426950408889634f;   // scale * log2(e)

    for (int kt = 0; kt < SEQ_L / 128; kt++) {
        __syncthreads();   // previous iter's frag reads done
        // ---- stage K-tile + V^T-tile (8 GLD16 per wave, no VGPR data) ----
#pragma unroll
        for (int j = 0; j < 4; j++) {
            int cid = wave * 4 + j;
            int kc = cid >> 1, key0 = (cid & 1) << 6;
            GLD16(Kbh + (size_t)(kt * 128 + key0 + lane) * D_MODEL + kc * 8,
                  &sK[cid * 512]);
            GLD16(Vbh + (size_t)lane * SEQ_L + kt * 128 + cid * 8,
                  &sV[cid * 512]);
        }
        __syncthreads();   // staging complete (vmcnt drained by barrier)

        // ---- mask loads (f32x4, indexed by key=row) ----
        f32x4 mkv[8];
#pragma unroll
        for (int sub = 0; sub < 8; sub++)
            mkv[sub] = *(const f32x4*)&mk[kt * 128 + sub * 16 + quad * 4];

        // ---- S^T = K·Q^T : D[m=key][n=q] ----
        f32x4 s[8];
#pragma unroll
        for (int sub = 0; sub < 8; sub++) {
            bf16x8 kf0 = *(const bf16x8*)&sK[(quad * 128 + sub * 16 + l15) * 8];
            bf16x8 kf1 = *(const bf16x8*)&sK[((quad + 4) * 128 + sub * 16 + l15) * 8];
            s[sub] = (f32x4){0.f, 0.f, 0.f, 0.f};
            s[sub] = MFMA16(kf0, qf0, s[sub]);
            s[sub] = MFMA16(kf1, qf1, s[sub]);
        }
        // ---- scale+mask in one FMA (log2 domain) ----
#pragma unroll
        for (int sub = 0; sub < 8; sub++)
#pragma unroll
            for (int r = 0; r < 4; r++) s[sub][r] = s[sub][r] * CSC + mkv[sub][r];

        // ---- per-lane max over 32 scores + 2 shuffles ----
        f32x4 mx4 = s[0];
#pragma unroll
        for (int sub = 1; sub < 8; sub++)
#pragma unroll
            for (int r = 0; r < 4; r++) mx4[r] = fmaxf(mx4[r], s[sub][r]);
        float pmax = fmaxf(fmaxf(mx4[0], mx4[1]), fmaxf(mx4[2], mx4[3]));
        pmax = fmaxf(pmax, __shfl_xor(pmax, 16));
        pmax = fmaxf(pmax, __shfl_xor(pmax, 32));
        float mnew = fmaxf(mrow, pmax);
        float alpha = EXP2F(mrow - mnew);
        mrow = mnew;
        if (quad == 0) sAl[wave][l15] = alpha;   // broadcast to O rows

        // ---- exp2 + pairwise pack + P writes ----
        float ls = 0.f;
#pragma unroll
        for (int sub = 0; sub < 8; sub++) {
            float p0 = EXP2F(s[sub][0] - mnew);
            float p1 = EXP2F(s[sub][1] - mnew);
            float p2 = EXP2F(s[sub][2] - mnew);
            float p3 = EXP2F(s[sub][3] - mnew);
            ls += (p0 + p1) + (p2 + p3);
            int2v pk = { pack2bf(p0, p1), pack2bf(p2, p3) };
            *(int2v*)&pslab[l15 * 136 + sub * 16 + quad * 4] = pk;
        }
        ls += __shfl_xor(ls, 16);
        ls += __shfl_xor(ls, 32);
        lrow = lrow * alpha + ls;

        // ---- rescale O by alpha (read per-row broadcast) ----
        f32x4 av = *(const f32x4*)&sAl[wave][quad * 4];
#pragma unroll
        for (int nt = 0; nt < 4; nt++)
#pragma unroll
            for (int r = 0; r < 4; r++) o4[nt][r] *= av[r];

        // ---- PV: P A-frags from slab, V B-frags from sV ----
        bf16x8 pf[4];
#pragma unroll
        for (int c = 0; c < 4; c++)
            pf[c] = *(const bf16x8*)&pslab[l15 * 136 + c * 32 + quad * 8];
#pragma unroll
        for (int nt = 0; nt < 4; nt++)
#pragma unroll
            for (int c = 0; c < 4; c++) {
                bf16x8 vfr = *(const bf16x8*)&sV[((c * 4 + quad) * 64 + nt * 16 + l15) * 8];
                o4[nt] = MFMA16(pf[c], vfr, o4[nt]);
            }
    }
    // final 1/l broadcast to O rows
    if (quad == 0) sAl[wave][l15] = 1.f / lrow;
    __syncthreads();   // harmless; also orders sAl
    f32x4 iv = *(const f32x4*)&sAl[wave][quad * 4];
#pragma unroll
    for (int nt = 0; nt < 4; nt++)
#pragma unroll
        for (int r = 0; r < 4; r++)
            O[(size_t)(qbase + wave * 16 + quad * 4 + r) * D_MODEL
              + h * HEAD_D + nt * 16 + l15] = f2bf(o4[nt][r] * iv[r]);
}

// ---------------------------------------------------------------------------
// Launch
// ---------------------------------------------------------------------------
extern "C" void kernel_launch(void* const* d_in, const int* in_sizes, int n_in,
                              void* d_out, int out_size, void* d_ws, size_t ws_size,
                              hipStream_t stream)
{
    const float* x     = (const float*)d_in[0];
    const int*   amask = (const int*)  d_in[1];
    const float* wq    = (const float*)d_in[2];
    const float* bq    = (const float*)d_in[3];
    const float* wk    = (const float*)d_in[4];
    const float* bk    = (const float*)d_in[5];
    const float* wv    = (const float*)d_in[6];
    const float* bv    = (const float*)d_in[7];
    const float* wo    = (const float*)d_in[8];
    const float* bo    = (const float*)d_in[9];
    const float* ln1s  = (const float*)d_in[10];
    const float* ln1b  = (const float*)d_in[11];
    const float* ln2s  = (const float*)d_in[12];
    const float* ln2b  = (const float*)d_in[13];
    const float* w1    = (const float*)d_in[14];
    const float* b1    = (const float*)d_in[15];
    const float* w2    = (const float*)d_in[16];
    const float* b2    = (const float*)d_in[17];
    float* out = (float*)d_out;

    // workspace layout (bytes; peak 104 MB, proven available)
    char* w = (char*)d_ws;
    short* wqkvt = (short*)(w + (size_t)0);          // [3072][1024] bf16, 6MB
    short* wot   = (short*)(w + ((size_t)6  << 20));
    short* w1t   = (short*)(w + ((size_t)8  << 20));
    short* w2t   = (short*)(w + ((size_t)16 << 20));
    short* hb    = (short*)(w + ((size_t)24 << 20)); // LN1 out, later LN2 out
    short* qb    = (short*)(w + ((size_t)40 << 20)); // qb,kbf contiguous:
    short* kbf   = (short*)(w + ((size_t)56 << 20)); //   16MB stride for qkv mode
    short* attnb = (short*)(w + ((size_t)72 << 20));
    short* vtb   = (short*)(w + ((size_t)88 << 20));
    short* ffb   = qb;   // q/k/vt dead by MLP1 (64 MB span 40..104)
    // fmask lives in the hb region (dead between QKV GEMM and LN2): 32KB
    float* fmaskb = (float*)(w + ((size_t)24 << 20));

    dim3 blk(256);

    // weight prep: W [K,N] fp32 -> W^T [N,K] bf16 (QKV stacked into one)
    transpose_cast<<<dim3(32, 32),  blk, 0, stream>>>(wq, wqkvt,              1024, 1024);
    transpose_cast<<<dim3(32, 32),  blk, 0, stream>>>(wk, wqkvt + 1024 * 1024, 1024, 1024);
    transpose_cast<<<dim3(32, 32),  blk, 0, stream>>>(wv, wqkvt + 2048 * 1024, 1024, 1024);
    transpose_cast<<<dim3(32, 32),  blk, 0, stream>>>(wo, wot, 1024, 1024);
    transpose_cast<<<dim3(128, 32), blk, 0, stream>>>(w1, w1t, 1024, 4096);
    transpose_cast<<<dim3(32, 128), blk, 0, stream>>>(w2, w2t, 4096, 1024);

    // 1) h = LN1(x) -> bf16
    ln_kernel<<<N_TOK, blk, 0, stream>>>(x, ln1s, ln1b, hb);

    // 2) fused QKV GEMM: writes qb, kbf, and V directly transposed (vtb)
    gemm_bf16<<<dim3(3 * D_MODEL / 128, N_TOK / 128), blk, 0, stream>>>(
        hb, 1024, wqkvt, 1024, bq, bk, bv, nullptr,
        nullptr, qb, vtb, 1024, 1024, 0, 1);

    // 2b) fp32 mask (into hb region — hb is dead until LN2 rewrites it)
    mask_kernel<<<dim3(8 * SEQ_L / 256), blk, 0, stream>>>(amask, fmaskb);

    // 3) flash attention -> attnb (bf16); 1-D grid, XCD swizzle inside
    attn_kernel<<<dim3(2048), blk, 0, stream>>>(qb, kbf, vtb, fmaskb, attnb);

    // 4) out = x + attn @ wo + bo  (fp32 out)
    gemm_bf16<<<dim3(D_MODEL / 128, N_TOK / 128), blk, 0, stream>>>(
        attnb, 1024, wot, 1024, bo, nullptr, nullptr, x,
        out, nullptr, nullptr, 1024, 1024, 0, 0);

    // 5) h = LN2(out) -> bf16
    ln_kernel<<<N_TOK, blk, 0, stream>>>(out, ln2s, ln2b, hb);

    // 6) MLP
    gemm_bf16<<<dim3(FF_DIM / 128, N_TOK / 128), blk, 0, stream>>>(
        hb, 1024, w1t, 1024, b1, nullptr, nullptr, nullptr,
        nullptr, ffb, nullptr, 4096, 1024, 1, 0);
    gemm_bf16<<<dim3(D_MODEL / 128, N_TOK / 128), blk, 0, stream>>>(
        ffb, 4096, w2t, 4096, b2, nullptr, nullptr, out,
        out, nullptr, nullptr, 1024, 4096, 0, 0);
}